// Round 1
// baseline (296.947 us; speedup 1.0000x reference)
//
#include <hip/hip_runtime.h>

typedef unsigned short u16;
typedef unsigned int u32;
typedef _Float16 half8 __attribute__((ext_vector_type(8)));
typedef float f32x16 __attribute__((ext_vector_type(16)));

union HU { uint4 u; half8 h; };

__device__ __forceinline__ u16 f2h(float f) {
  union { _Float16 h; u16 u; } c;
  c.h = (_Float16)f;
  return c.u;
}

// LDS element offset: [row][w][c] with XOR swizzle c' = c ^ ((w&7)<<3).
// Keeps 8-element c-blocks contiguous (b128 reads) and conflict-free banking.
__device__ __forceinline__ int ldsoff(int row, int w, int c) {
  return ((row * 128 + w) * 64) + (c ^ ((w & 7) << 3));
}

// Pack weights (O=64, I=64, 3, 3) fp32 -> fp16 in exact A-fragment order:
// wbuf[((t*2 + mt)*64 + lane)*8 + j] = w[m][c][rs]
//   m = mt*32 + (lane&31), k = t*16 + (lane>>5)*8 + j, rs = k>>6, c = k&63
// K ordering: k = rs*64 + c  (rs-major, c-minor)
__global__ void prep_w(const float* __restrict__ w, u16* __restrict__ wbuf) {
  int idx = blockIdx.x * 256 + threadIdx.x;  // 36864 total
  int j    = idx & 7;
  int lane = (idx >> 3) & 63;
  int mt   = (idx >> 9) & 1;
  int t    = idx >> 10;
  int m  = mt * 32 + (lane & 31);
  int k  = t * 16 + (lane >> 5) * 8 + j;
  int rs = k >> 6;
  int c  = k & 63;
  wbuf[idx] = f2h(w[(m * 64 + c) * 9 + rs]);
}

// Implicit-GEMM conv: M = O = 64 (2 mtiles of 32), N = pixels, K = 576 (36 ktiles of 16)
// Block: one n, 2 output rows (h0, h0+1), 128 w, all 64 o.  256 threads = 4 waves.
// Wave: rw = wave>>1 (row), ntp = wave&1 (pixel half); 2 mtiles x 2 ntiles of 32 pixels.
__global__ __launch_bounds__(256, 2) void conv_mfma(
    const float* __restrict__ x, const u16* __restrict__ wbuf,
    const float* __restrict__ bias, float* __restrict__ out) {
  __shared__ u16 xlds[4 * 128 * 64];  // 64 KB: rows h0-1 .. h0+2, fp16, c-fastest

  int tid = threadIdx.x;
  int bid = blockIdx.x;
  int nb = bid & 31;   // batch
  int hg = bid >> 5;   // row-group [0,64)
  int h0 = hg * 2;

  // ---- zero rows whose input row is out of bounds (h padding) ----
#pragma unroll
  for (int rr = 0; rr < 4; ++rr) {
    int hin = h0 - 1 + rr;
    if (hin < 0 || hin >= 128) {
      uint4 z = make_uint4(0u, 0u, 0u, 0u);
      for (int i = tid; i < 1024; i += 256)  // 1024 x 16B = one 16KB row
        ((uint4*)xlds)[rr * 1024 + i] = z;
    }
  }

  // ---- stage x -> LDS (fp32 -> fp16, transpose to c-fastest, swizzled) ----
  // item = (row[4], cpair[32], wq[32]); lane&31 -> cpair keeps LDS writes conflict-free
  {
    int cpair = (tid & 31) * 2;
    int sub = tid >> 5;  // 0..7
#pragma unroll
    for (int it = 0; it < 16; ++it) {
      int combo = it * 8 + sub;   // 0..127
      int row = combo >> 5;       // 0..3
      int wq = combo & 31;        // 0..31 (4 w each)
      int hin = h0 - 1 + row;
      if (hin >= 0 && hin < 128) {
        const float* base = x + ((nb * 64 + cpair) * 128 + hin) * 128 + wq * 4;
        float4 va = *(const float4*)base;            // channel cpair
        float4 vb = *(const float4*)(base + 16384);  // channel cpair+1
        int w = wq * 4;
        u32 p0 = (u32)f2h(va.x) | ((u32)f2h(vb.x) << 16);
        u32 p1 = (u32)f2h(va.y) | ((u32)f2h(vb.y) << 16);
        u32 p2 = (u32)f2h(va.z) | ((u32)f2h(vb.z) << 16);
        u32 p3 = (u32)f2h(va.w) | ((u32)f2h(vb.w) << 16);
        *(u32*)&xlds[ldsoff(row, w + 0, cpair)] = p0;
        *(u32*)&xlds[ldsoff(row, w + 1, cpair)] = p1;
        *(u32*)&xlds[ldsoff(row, w + 2, cpair)] = p2;
        *(u32*)&xlds[ldsoff(row, w + 3, cpair)] = p3;
      }
    }
  }
  __syncthreads();

  // ---- K-loop ----
  int lane = tid & 63;
  int wave = tid >> 6;     // 0..3
  int rw = wave >> 1;      // output row within block
  int ntp = wave & 1;      // pixel half
  int l31 = lane & 31;
  int half = lane >> 5;
  int p0 = ntp * 64 + l31;  // pixel of ntile 2*ntp
  int p1 = p0 + 32;         // pixel of ntile 2*ntp+1

  f32x16 acc[2][2] = {};  // [mt][ntile]

#pragma unroll 4
  for (int t = 0; t < 36; ++t) {
    int rs = t >> 2;         // 0..8
    int r = rs / 3;          // kernel row 0..2
    int s = rs - 3 * r;      // kernel col 0..2
    int c0 = (t & 3) * 16 + half * 8;
    int row = rw + r;

    int pin0 = p0 + s - 1;
    int pin1 = p1 + s - 1;
    bool ob0 = (unsigned)pin0 >= 128u;
    bool ob1 = (unsigned)pin1 >= 128u;

    HU b0, b1, a0, a1;
    b0.u = *(const uint4*)&xlds[ldsoff(row, ob0 ? 0 : pin0, c0)];
    b1.u = *(const uint4*)&xlds[ldsoff(row, ob1 ? 0 : pin1, c0)];
    if (ob0) b0.u = make_uint4(0u, 0u, 0u, 0u);
    if (ob1) b1.u = make_uint4(0u, 0u, 0u, 0u);

    a0.u = *(const uint4*)&wbuf[(t * 2 + 0) * 512 + lane * 8];
    a1.u = *(const uint4*)&wbuf[(t * 2 + 1) * 512 + lane * 8];

    acc[0][0] = __builtin_amdgcn_mfma_f32_32x32x16_f16(a0.h, b0.h, acc[0][0], 0, 0, 0);
    acc[1][0] = __builtin_amdgcn_mfma_f32_32x32x16_f16(a1.h, b0.h, acc[1][0], 0, 0, 0);
    acc[0][1] = __builtin_amdgcn_mfma_f32_32x32x16_f16(a0.h, b1.h, acc[0][1], 0, 0, 0);
    acc[1][1] = __builtin_amdgcn_mfma_f32_32x32x16_f16(a1.h, b1.h, acc[1][1], 0, 0, 0);
  }

  // ---- epilogue: C/D layout col = lane&31 (pixel), row = (reg&3)+8*(reg>>2)+4*half (o) ----
  int h = h0 + rw;
  size_t outbase = (size_t)nb * 64 * 16384 + (size_t)h * 128;
#pragma unroll
  for (int mt = 0; mt < 2; ++mt) {
#pragma unroll
    for (int q = 0; q < 2; ++q) {
      int p = q ? p1 : p0;
#pragma unroll
      for (int reg = 0; reg < 16; ++reg) {
        int o = mt * 32 + (reg & 3) + 8 * (reg >> 2) + 4 * half;
        out[outbase + (size_t)o * 16384 + p] = acc[mt][q][reg] + bias[o];
      }
    }
  }
}

extern "C" void kernel_launch(void* const* d_in, const int* in_sizes, int n_in,
                              void* d_out, int out_size, void* d_ws, size_t ws_size,
                              hipStream_t stream) {
  const float* x = (const float*)d_in[0];
  const float* w = (const float*)d_in[1];
  const float* b = (const float*)d_in[2];
  float* out = (float*)d_out;
  u16* wbuf = (u16*)d_ws;  // 36864 fp16 = 73728 B of scratch

  prep_w<<<dim3(144), dim3(256), 0, stream>>>(w, wbuf);
  conv_mfma<<<dim3(2048), dim3(256), 0, stream>>>(x, wbuf, b, out);
}

// Round 3
// 289.125 us; speedup vs baseline: 1.0271x; 1.0271x over previous
//
#include <hip/hip_runtime.h>

typedef unsigned short u16;
typedef unsigned int u32;
typedef _Float16 half8 __attribute__((ext_vector_type(8)));
typedef __fp16 fp16x2 __attribute__((ext_vector_type(2)));
typedef float f32x16 __attribute__((ext_vector_type(16)));

union HU { uint4 u; half8 h; };
union PK { fp16x2 h; u32 u; };

__device__ __forceinline__ u16 f2h(float f) {
  union { _Float16 h; u16 u; } c;
  c.h = (_Float16)f;
  return c.u;
}

// Pack weights (O=64, I=64, 3, 3) fp32 -> fp16 in exact A-fragment order:
// wbuf[((t*2 + mt)*64 + lane)*8 + j] = w[m][c][rs]
//   m = mt*32 + (lane&31), k = t*16 + (lane>>5)*8 + j, rs = k>>6, c = k&63
// K ordering: k = rs*64 + c  (rs-major, c-minor); rs = kh*3+kw
__global__ void prep_w(const float* __restrict__ w, u16* __restrict__ wbuf) {
  int idx = blockIdx.x * 256 + threadIdx.x;  // 36864 total
  int j    = idx & 7;
  int lane = (idx >> 3) & 63;
  int mt   = (idx >> 9) & 1;
  int t    = idx >> 10;
  int m  = mt * 32 + (lane & 31);
  int k  = t * 16 + (lane >> 5) * 8 + j;
  int rs = k >> 6;
  int c  = k & 63;
  wbuf[idx] = f2h(w[(m * 64 + c) * 9 + rs]);
}

// Implicit-GEMM conv: M = O = 64 (2 mtiles), N = pixels, K = 576 (36 ktiles of 16)
// Block: one n, 2 output rows, 128 w, all 64 o.  512 threads = 8 waves.
// Wave = (rw = wave>>2, nq = wave&3): one output row, one 32-pixel ntile, both mtiles.
// LDS: [row 4][cblk 8][w 128][c 8] fp16 (64 KB) — no swizzle needed:
//   staging writes are lane->w stride-16B b128 (conflict-free),
//   K-loop B reads are lane->pixel stride-16B b128 (conflict-free).
__global__ __launch_bounds__(512, 4) void conv_mfma(
    const float* __restrict__ x, const u16* __restrict__ wbuf,
    const float* __restrict__ bias, float* __restrict__ out) {
  __shared__ u16 xlds[4 * 8 * 128 * 8];  // 64 KB

  int tid = threadIdx.x;
  int lane = tid & 63;
  int wave = tid >> 6;  // 0..7
  int bid = blockIdx.x;
  int nb = bid & 31;   // batch
  int hg = bid >> 5;   // row-group [0,64)
  int h0 = hg * 2;

  // ---- stage x -> LDS, coalesced (lane->w), register transpose 8c via pkrtz ----
  // slab = (row[4], cblk[8]) = 32 slabs; wave handles 4; lane covers w and w+64.
#pragma unroll
  for (int s = 0; s < 4; ++s) {
    int id = wave * 4 + s;   // 0..31
    int row = id >> 3;       // 0..3
    int cblk = id & 7;
    int hin = h0 - 1 + row;
    int c0 = cblk * 8;
    bool inb = (hin >= 0 && hin < 128);
    const float* base = x + (((size_t)(nb * 64 + c0) * 128 + hin) * 128);
#pragma unroll
    for (int w2 = 0; w2 < 2; ++w2) {
      int w = w2 * 64 + lane;
      uint4 v = make_uint4(0u, 0u, 0u, 0u);
      if (inb) {
        float f[8];
#pragma unroll
        for (int j = 0; j < 8; ++j) f[j] = base[(size_t)j * 16384 + w];
        PK p0, p1, p2, p3;
        p0.h = __builtin_amdgcn_cvt_pkrtz(f[0], f[1]);
        p1.h = __builtin_amdgcn_cvt_pkrtz(f[2], f[3]);
        p2.h = __builtin_amdgcn_cvt_pkrtz(f[4], f[5]);
        p3.h = __builtin_amdgcn_cvt_pkrtz(f[6], f[7]);
        v = make_uint4(p0.u, p1.u, p2.u, p3.u);
      }
      *(uint4*)&xlds[(id * 128 + w) * 8] = v;
    }
  }
  __syncthreads();

  // ---- K-loop ----
  int l31 = lane & 31;
  int half = lane >> 5;
  int rw = wave >> 2;      // output row within block
  int nq = wave & 3;       // 32-pixel ntile
  int p = nq * 32 + l31;   // this lane's pixel (B-frag col)

  f32x16 acc[2] = {};      // [mt]

#pragma unroll
  for (int r = 0; r < 3; ++r) {
    int row = rw + r;  // LDS row index (input row h0-1+row)
#pragma unroll
    for (int s = 0; s < 3; ++s) {
      int pin = p + s - 1;
      bool ob = (unsigned)pin >= 128u;
      int pc = ob ? 0 : pin;
#pragma unroll
      for (int tc = 0; tc < 4; ++tc) {
        int t = ((r * 3 + s) * 4) + tc;
        int cblk = tc * 2 + half;
        HU b, a0, a1;
        b.u = *(const uint4*)&xlds[((row * 8 + cblk) * 128 + pc) * 8];
        if (ob) b.u = make_uint4(0u, 0u, 0u, 0u);
        a0.u = *(const uint4*)&wbuf[(t * 2 + 0) * 512 + lane * 8];
        a1.u = *(const uint4*)&wbuf[(t * 2 + 1) * 512 + lane * 8];
        acc[0] = __builtin_amdgcn_mfma_f32_32x32x16_f16(a0.h, b.h, acc[0], 0, 0, 0);
        acc[1] = __builtin_amdgcn_mfma_f32_32x32x16_f16(a1.h, b.h, acc[1], 0, 0, 0);
      }
    }
  }

  // ---- epilogue: C/D layout col = lane&31 (pixel), row = (reg&3)+8*(reg>>2)+4*half (o) ----
  int h = h0 + rw;
  size_t outbase = (size_t)nb * 64 * 16384 + (size_t)h * 128 + p;
#pragma unroll
  for (int mt = 0; mt < 2; ++mt) {
#pragma unroll
    for (int reg = 0; reg < 16; ++reg) {
      int o = mt * 32 + (reg & 3) + 8 * (reg >> 2) + 4 * half;
      out[outbase + (size_t)o * 16384] = acc[mt][reg] + bias[o];
    }
  }
}

extern "C" void kernel_launch(void* const* d_in, const int* in_sizes, int n_in,
                              void* d_out, int out_size, void* d_ws, size_t ws_size,
                              hipStream_t stream) {
  const float* x = (const float*)d_in[0];
  const float* w = (const float*)d_in[1];
  const float* b = (const float*)d_in[2];
  float* out = (float*)d_out;
  u16* wbuf = (u16*)d_ws;  // 36864 fp16 = 73728 B of scratch

  prep_w<<<dim3(144), dim3(256), 0, stream>>>(w, wbuf);
  conv_mfma<<<dim3(2048), dim3(512), 0, stream>>>(x, wbuf, b, out);
}